// Round 1
// baseline (758.699 us; speedup 1.0000x reference)
//
#include <hip/hip_runtime.h>
#include <hip/hip_bf16.h>

// Problem constants (fixed by the reference)
#define HD   4096      // hidden
#define ID   14336     // intermediate
#define NB   64        // batch
#define NLUTN 4096
#define KSPLIT 4       // down-proj K split across grid.y

typedef __attribute__((ext_vector_type(8))) short short8;   // 8 x bf16 bits = 4 VGPRs
typedef __attribute__((ext_vector_type(4))) float f32x4;    // MFMA accumulator

__device__ __forceinline__ unsigned short f2bf(float f) {
  __hip_bfloat16 h = __float2bfloat16(f);
  return __builtin_bit_cast(unsigned short, h);
}

// ---------------------------------------------------------------------------
// prep: x'_g[b][h] = bf16(x[b][h]*gsr[h]), x'_u likewise. 64*4096 elements.
// ---------------------------------------------------------------------------
__global__ __launch_bounds__(256) void prep_kernel(
    const float* __restrict__ x, const float* __restrict__ gsr,
    const float* __restrict__ usr,
    unsigned short* __restrict__ xg, unsigned short* __restrict__ xu)
{
  int t = blockIdx.x * 256 + threadIdx.x;          // 0..65535 float4s
  float4 xv = ((const float4*)x)[t];
  int hs = t & (HD/4 - 1);                         // float4 index within row
  float4 g = ((const float4*)gsr)[hs];
  float4 u = ((const float4*)usr)[hs];
  ushort4 og = make_ushort4(f2bf(xv.x*g.x), f2bf(xv.y*g.y), f2bf(xv.z*g.z), f2bf(xv.w*g.w));
  ushort4 ou = make_ushort4(f2bf(xv.x*u.x), f2bf(xv.y*u.y), f2bf(xv.z*u.z), f2bf(xv.w*u.w));
  ((ushort4*)xg)[t] = og;
  ((ushort4*)xu)[t] = ou;
}

// ---------------------------------------------------------------------------
// gate+up: one BLOCK (4 waves) per 16-row I-strip. Waves K-split 4096 -> 4x1024.
// Depth-1 register prefetch of the int32 code stream (HBM latency overlap).
// LDS reduce of partial accumulators; wave0 does the silu*up*dsr epilogue.
// grid = ID/16 = 896 blocks x 256 thr. LDS: 16KB LUT + 24KB reduce = 40KB.
// ---------------------------------------------------------------------------
__global__ __launch_bounds__(256, 4) void gate_up_kernel(
    const int* __restrict__ gw, const int* __restrict__ uw,
    const float* __restrict__ lutg_f, const float* __restrict__ lutu_f,
    const unsigned short* __restrict__ xg, const unsigned short* __restrict__ xu,
    const float* __restrict__ gsl, const float* __restrict__ usl,
    const float* __restrict__ dsr,
    unsigned short* __restrict__ hidden)
{
  __shared__ unsigned short lutg[NLUTN];
  __shared__ unsigned short lutu[NLUTN];
  __shared__ f32x4 red[3][8][64];        // [src wave-1][t: 0..3 gate, 4..7 up][lane]

  const int tid  = threadIdx.x;          // 0..255
  const int lane = tid & 63;
  const int w    = tid >> 6;             // wave 0..3

  // Stage LUTs as bf16 bits (8 KB each), all 256 threads
  #pragma unroll
  for (int i = tid; i < NLUTN/4; i += 256) {
    float4 g = ((const float4*)lutg_f)[i];
    float4 u = ((const float4*)lutu_f)[i];
    ((ushort4*)lutg)[i] = make_ushort4(f2bf(g.x), f2bf(g.y), f2bf(g.z), f2bf(g.w));
    ((ushort4*)lutu)[i] = make_ushort4(f2bf(u.x), f2bf(u.y), f2bf(u.z), f2bf(u.w));
  }
  __syncthreads();

  const int col  = lane & 15;   // A: row-within-strip; B: batch-within-tile; D: batch col
  const int quad = lane >> 4;
  const int m0   = blockIdx.x * 16;

  // per-wave K chunk
  const int kbeg = w * (HD / 4);         // 1024-wide chunks
  const int kend = kbeg + (HD / 4);

  const int* gp = gw + (size_t)(m0 + col) * HD + quad * 8;
  const int* up = uw + (size_t)(m0 + col) * HD + quad * 8;
  const unsigned short* xgp[4];
  const unsigned short* xup[4];
  #pragma unroll
  for (int t = 0; t < 4; ++t) {
    xgp[t] = xg + (size_t)(t*16 + col) * HD + quad * 8;
    xup[t] = xu + (size_t)(t*16 + col) * HD + quad * 8;
  }

  const f32x4 z = {0.f, 0.f, 0.f, 0.f};
  f32x4 accg[4] = {z, z, z, z};
  f32x4 accu[4] = {z, z, z, z};

  // depth-1 prefetch: codes for k = kbeg already in flight when loop starts
  int4 cga = *(const int4*)(gp + kbeg);
  int4 cgb = *(const int4*)(gp + kbeg + 4);
  int4 cua = *(const int4*)(up + kbeg);
  int4 cub = *(const int4*)(up + kbeg + 4);

  for (int k0 = kbeg; k0 < kend; k0 += 32) {
    // issue next iteration's code loads FIRST (address is data-independent)
    int kn = k0 + 32;
    if (kn >= kend) kn = kbeg;           // harmless dummy on last iter
    int4 nga = *(const int4*)(gp + kn);
    int4 ngb = *(const int4*)(gp + kn + 4);
    int4 nua = *(const int4*)(up + kn);
    int4 nub = *(const int4*)(up + kn + 4);

    // LDS gather from the codes prefetched last iteration
    short8 afg, afu;
    afg[0] = (short)lutg[cga.x]; afg[1] = (short)lutg[cga.y];
    afg[2] = (short)lutg[cga.z]; afg[3] = (short)lutg[cga.w];
    afg[4] = (short)lutg[cgb.x]; afg[5] = (short)lutg[cgb.y];
    afg[6] = (short)lutg[cgb.z]; afg[7] = (short)lutg[cgb.w];
    afu[0] = (short)lutu[cua.x]; afu[1] = (short)lutu[cua.y];
    afu[2] = (short)lutu[cua.z]; afu[3] = (short)lutu[cua.w];
    afu[4] = (short)lutu[cub.x]; afu[5] = (short)lutu[cub.y];
    afu[6] = (short)lutu[cub.z]; afu[7] = (short)lutu[cub.w];

    #pragma unroll
    for (int t = 0; t < 4; ++t) {
      short8 bg = __builtin_bit_cast(short8, *(const int4*)(xgp[t] + k0));
      short8 bu = __builtin_bit_cast(short8, *(const int4*)(xup[t] + k0));
      accg[t] = __builtin_amdgcn_mfma_f32_16x16x32_bf16(afg, bg, accg[t], 0, 0, 0);
      accu[t] = __builtin_amdgcn_mfma_f32_16x16x32_bf16(afu, bu, accu[t], 0, 0, 0);
    }

    cga = nga; cgb = ngb; cua = nua; cub = nub;
  }

  // cross-wave reduce through LDS (lane-major f32x4 -> conflict-free b128)
  if (w > 0) {
    #pragma unroll
    for (int t = 0; t < 4; ++t) {
      red[w-1][t][lane]     = accg[t];
      red[w-1][4 + t][lane] = accu[t];
    }
  }
  __syncthreads();
  if (w == 0) {
    #pragma unroll
    for (int ww = 0; ww < 3; ++ww) {
      #pragma unroll
      for (int t = 0; t < 4; ++t) {
        accg[t] += red[ww][t][lane];
        accu[t] += red[ww][4 + t][lane];
      }
    }

    // Epilogue. D mapping: col = lane&15 (batch), row = quad*4 + reg (i).
    const int mrow = m0 + quad * 4;
    float sg[4], su[4], sd[4];
    #pragma unroll
    for (int r = 0; r < 4; ++r) {
      sg[r] = 0.02f * gsl[mrow + r];
      su[r] = 0.02f * usl[mrow + r];
      sd[r] = dsr[mrow + r];
    }
    #pragma unroll
    for (int t = 0; t < 4; ++t) {
      int b = t*16 + col;
      ushort4 hv;
      float g0 = accg[t][0] * sg[0], u0 = accu[t][0] * su[0];
      float g1 = accg[t][1] * sg[1], u1 = accu[t][1] * su[1];
      float g2 = accg[t][2] * sg[2], u2 = accu[t][2] * su[2];
      float g3 = accg[t][3] * sg[3], u3 = accu[t][3] * su[3];
      hv.x = f2bf((g0 / (1.f + __expf(-g0))) * u0 * sd[0]);
      hv.y = f2bf((g1 / (1.f + __expf(-g1))) * u1 * sd[1]);
      hv.z = f2bf((g2 / (1.f + __expf(-g2))) * u2 * sd[2]);
      hv.w = f2bf((g3 / (1.f + __expf(-g3))) * u3 * sd[3]);
      *((ushort4*)(hidden + (size_t)b * ID + mrow)) = hv;
    }
  }
}

// ---------------------------------------------------------------------------
// down: out[b][h] = 0.02*dsl[h] * sum_i hidden[b][i]*lut_d[dw[h,i]]
// grid (HD/16, KSPLIT) blocks of 4 waves; waves K-split within the block's
// K range; LDS reduce; wave0 does one atomicAdd set per block.
// LDS: 8KB LUT + 12KB reduce = 20KB.
// ---------------------------------------------------------------------------
__global__ __launch_bounds__(256, 4) void down_kernel(
    const int* __restrict__ dw, const float* __restrict__ lutd_f,
    const unsigned short* __restrict__ hidden,
    const float* __restrict__ dsl,
    float* __restrict__ out)
{
  __shared__ unsigned short lutd[NLUTN];
  __shared__ f32x4 red[3][4][64];

  const int tid  = threadIdx.x;
  const int lane = tid & 63;
  const int w    = tid >> 6;

  #pragma unroll
  for (int i = tid; i < NLUTN/4; i += 256) {
    float4 d = ((const float4*)lutd_f)[i];
    ((ushort4*)lutd)[i] = make_ushort4(f2bf(d.x), f2bf(d.y), f2bf(d.z), f2bf(d.w));
  }
  __syncthreads();

  const int col  = lane & 15;
  const int quad = lane >> 4;
  const int m0   = blockIdx.x * 16;                    // h strip
  const int kchunk = ID / KSPLIT;                      // 3584
  const int kbeg = blockIdx.y * kchunk + w * (kchunk / 4);   // per-wave 896
  const int kend = kbeg + kchunk / 4;

  const int* dp = dw + (size_t)(m0 + col) * ID + quad * 8;
  const unsigned short* hp[4];
  #pragma unroll
  for (int t = 0; t < 4; ++t)
    hp[t] = hidden + (size_t)(t*16 + col) * ID + quad * 8;

  const f32x4 z = {0.f, 0.f, 0.f, 0.f};
  f32x4 acc[4] = {z, z, z, z};

  int4 cda = *(const int4*)(dp + kbeg);
  int4 cdb = *(const int4*)(dp + kbeg + 4);

  for (int k0 = kbeg; k0 < kend; k0 += 32) {
    int kn = k0 + 32;
    if (kn >= kend) kn = kbeg;
    int4 nda = *(const int4*)(dp + kn);
    int4 ndb = *(const int4*)(dp + kn + 4);

    short8 af;
    af[0] = (short)lutd[cda.x]; af[1] = (short)lutd[cda.y];
    af[2] = (short)lutd[cda.z]; af[3] = (short)lutd[cda.w];
    af[4] = (short)lutd[cdb.x]; af[5] = (short)lutd[cdb.y];
    af[6] = (short)lutd[cdb.z]; af[7] = (short)lutd[cdb.w];

    #pragma unroll
    for (int t = 0; t < 4; ++t) {
      short8 bh = __builtin_bit_cast(short8, *(const int4*)(hp[t] + k0));
      acc[t] = __builtin_amdgcn_mfma_f32_16x16x32_bf16(af, bh, acc[t], 0, 0, 0);
    }

    cda = nda; cdb = ndb;
  }

  if (w > 0) {
    #pragma unroll
    for (int t = 0; t < 4; ++t) red[w-1][t][lane] = acc[t];
  }
  __syncthreads();
  if (w == 0) {
    #pragma unroll
    for (int ww = 0; ww < 3; ++ww) {
      #pragma unroll
      for (int t = 0; t < 4; ++t) acc[t] += red[ww][t][lane];
    }

    const int mrow = m0 + quad * 4;
    float sc[4];
    #pragma unroll
    for (int r = 0; r < 4; ++r) sc[r] = 0.02f * dsl[mrow + r];
    #pragma unroll
    for (int t = 0; t < 4; ++t) {
      int b = t*16 + col;
      #pragma unroll
      for (int r = 0; r < 4; ++r)
        atomicAdd(&out[(size_t)b * HD + mrow + r], acc[t][r] * sc[r]);
    }
  }
}

// ---------------------------------------------------------------------------
extern "C" void kernel_launch(void* const* d_in, const int* in_sizes, int n_in,
                              void* d_out, int out_size, void* d_ws, size_t ws_size,
                              hipStream_t stream) {
  const float* x    = (const float*)d_in[0];
  const float* lutg = (const float*)d_in[1];
  const float* lutu = (const float*)d_in[2];
  const float* lutd = (const float*)d_in[3];
  const int*   gw   = (const int*)d_in[4];
  const int*   uw   = (const int*)d_in[5];
  const int*   dw   = (const int*)d_in[6];
  const float* gsl  = (const float*)d_in[7];
  const float* gsr  = (const float*)d_in[8];
  const float* usl  = (const float*)d_in[9];
  const float* usr  = (const float*)d_in[10];
  const float* dsl  = (const float*)d_in[11];
  const float* dsr  = (const float*)d_in[12];
  float* out = (float*)d_out;

  // ws layout: xg (512KB) | xu (512KB) | hidden (1.75MB)  -> ~2.75 MB total
  unsigned short* xg     = (unsigned short*)d_ws;
  unsigned short* xu     = xg + (size_t)NB * HD;
  unsigned short* hidden = xu + (size_t)NB * HD;

  hipMemsetAsync(d_out, 0, (size_t)NB * HD * sizeof(float), stream);
  prep_kernel<<<(NB*HD/4 + 255)/256, 256, 0, stream>>>(x, gsr, usr, xg, xu);
  gate_up_kernel<<<ID/16, 256, 0, stream>>>(gw, uw, lutg, lutu, xg, xu,
                                            gsl, usl, dsr, hidden);
  down_kernel<<<dim3(HD/16, KSPLIT), 256, 0, stream>>>(dw, lutd, hidden, dsl, out);
}

// Round 2
// 655.521 us; speedup vs baseline: 1.1574x; 1.1574x over previous
//
#include <hip/hip_runtime.h>
#include <hip/hip_bf16.h>

// Problem constants (fixed by the reference)
#define HD   4096      // hidden
#define ID   14336     // intermediate
#define NB   64        // batch
#define NLUTN 4096
#define DKS  8         // down-proj K split across grid.y

typedef __attribute__((ext_vector_type(8))) short short8;   // 8 x bf16 bits
typedef __attribute__((ext_vector_type(4))) float f32x4;    // MFMA accumulator

__device__ __forceinline__ unsigned short f2bf(float f) {
  __hip_bfloat16 h = __float2bfloat16(f);
  return __builtin_bit_cast(unsigned short, h);
}

// async global->LDS, 16B per lane, dest = uniform base + lane*16 (linear)
__device__ __forceinline__ void gll16(const int* g, void* l) {
  __builtin_amdgcn_global_load_lds(
      (const __attribute__((address_space(1))) int*)g,
      (__attribute__((address_space(3))) int*)l, 16, 0, 0);
}

// ---------------------------------------------------------------------------
// prep: k-blocked bf16 activations. xgB[k>>3][b][k&7] = bf16(x[b][k]*gsr[k]),
// xuB likewise. Unit u = k8*64+b -> 16B. 32768 units.
// ---------------------------------------------------------------------------
__global__ __launch_bounds__(256) void prep_kernel(
    const float* __restrict__ x, const float* __restrict__ gsr,
    const float* __restrict__ usr,
    unsigned short* __restrict__ xgB, unsigned short* __restrict__ xuB)
{
  int u = blockIdx.x * 256 + threadIdx.x;     // 0..32767
  int b = u & 63, k8 = u >> 6;
  const float* xp = x + (size_t)b * HD + k8 * 8;
  float4 x0 = ((const float4*)xp)[0];
  float4 x1 = ((const float4*)xp)[1];
  const float* gp = gsr + k8 * 8;
  const float* up = usr + k8 * 8;
  float4 g0 = ((const float4*)gp)[0], g1 = ((const float4*)gp)[1];
  float4 u0 = ((const float4*)up)[0], u1 = ((const float4*)up)[1];
  ushort4 og0 = make_ushort4(f2bf(x0.x*g0.x), f2bf(x0.y*g0.y), f2bf(x0.z*g0.z), f2bf(x0.w*g0.w));
  ushort4 og1 = make_ushort4(f2bf(x1.x*g1.x), f2bf(x1.y*g1.y), f2bf(x1.z*g1.z), f2bf(x1.w*g1.w));
  ushort4 ou0 = make_ushort4(f2bf(x0.x*u0.x), f2bf(x0.y*u0.y), f2bf(x0.z*u0.z), f2bf(x0.w*u0.w));
  ushort4 ou1 = make_ushort4(f2bf(x1.x*u1.x), f2bf(x1.y*u1.y), f2bf(x1.z*u1.z), f2bf(x1.w*u1.w));
  ((ushort4*)(xgB + (size_t)u*8))[0] = og0;
  ((ushort4*)(xgB + (size_t)u*8))[1] = og1;
  ((ushort4*)(xuB + (size_t)u*8))[0] = ou0;
  ((ushort4*)(xuB + (size_t)u*8))[1] = ou1;
}

// ---------------------------------------------------------------------------
// gate+up. Block = 128 thr = 2 waves. Wave w: 32 I-rows (2 strips of 16),
// K-half w (2048), 64 iters of k-32. Codes staged coalesced via
// global_load_lds into per-wave double-buffered, XOR-swizzled LDS chunks.
// x read from k-blocked layout (4-segment coalesced). LDS reduce of the
// two K-halves; wave0 epilogue writes hidden in k-blocked layout.
// grid = ID/32 = 448. LDS: 16K LUT + 32K codes + 16K red = 64KB.
// ---------------------------------------------------------------------------
__global__ __launch_bounds__(128, 2) void gate_up_kernel(
    const int* __restrict__ gw, const int* __restrict__ uw,
    const float* __restrict__ lutg_f, const float* __restrict__ lutu_f,
    const unsigned short* __restrict__ xgB, const unsigned short* __restrict__ xuB,
    const float* __restrict__ gsl, const float* __restrict__ usl,
    const float* __restrict__ dsr,
    unsigned short* __restrict__ hidB)
{
  __shared__ unsigned short lutg[NLUTN];
  __shared__ unsigned short lutu[NLUTN];
  __shared__ __align__(16) int cbuf[2][2][2][2][512]; // [wave][buf][mat][strip][16r*32k]
  __shared__ f32x4 red[16][64];

  const int tid  = threadIdx.x;
  const int lane = tid & 63;
  const int w    = tid >> 6;

  for (int i = tid; i < NLUTN/4; i += 128) {
    float4 g = ((const float4*)lutg_f)[i];
    float4 u = ((const float4*)lutu_f)[i];
    ((ushort4*)lutg)[i] = make_ushort4(f2bf(g.x), f2bf(g.y), f2bf(g.z), f2bf(g.w));
    ((ushort4*)lutu)[i] = make_ushort4(f2bf(u.x), f2bf(u.y), f2bf(u.z), f2bf(u.w));
  }
  __syncthreads();

  const int col  = lane & 15;
  const int quad = lane >> 4;
  const int m0   = blockIdx.x * 32;
  const int r8   = lane >> 3;          // staging: row within 8-row half
  const int j    = lane & 7;           // staging: 16B unit within row
  const int jx   = (j ^ r8) << 2;      // pre-swizzled src offset (ints)
  const int xsw  = (col & 7) << 4;     // read-side XOR (bytes)

  const int kbeg = w * (HD/2);         // 2048 per wave
  const int NIT  = (HD/2) / 32;        // 64

  const int* gsrc[2][2];
  const int* usrc[2][2];
  #pragma unroll
  for (int s = 0; s < 2; ++s)
    #pragma unroll
    for (int h = 0; h < 2; ++h) {
      int row = m0 + s*16 + h*8 + r8;
      gsrc[s][h] = gw + (size_t)row * HD + jx;
      usrc[s][h] = uw + (size_t)row * HD + jx;
    }

  const f32x4 z = {0.f, 0.f, 0.f, 0.f};
  f32x4 accg[2][4] = {{z,z,z,z},{z,z,z,z}};
  f32x4 accu[2][4] = {{z,z,z,z},{z,z,z,z}};

  // prologue: stage chunk 0 into buf 0
  #pragma unroll
  for (int s = 0; s < 2; ++s)
    #pragma unroll
    for (int h = 0; h < 2; ++h) {
      gll16(gsrc[s][h] + kbeg, (char*)&cbuf[w][0][0][s][0] + h*1024);
      gll16(usrc[s][h] + kbeg, (char*)&cbuf[w][0][1][s][0] + h*1024);
    }

  int p = 0;
  for (int it = 0; it < NIT; ++it) {
    const int k0 = kbeg + it*32;
    asm volatile("s_waitcnt vmcnt(0)" ::: "memory");   // buf p staged
    __builtin_amdgcn_sched_barrier(0);

    // codes from swizzled LDS + LUT gather
    short8 afg[2], afu[2];
    #pragma unroll
    for (int s = 0; s < 2; ++s) {
      const char* cg = (const char*)&cbuf[w][p][0][s][0];
      const char* cu = (const char*)&cbuf[w][p][1][s][0];
      int4 ga = *(const int4*)(cg + col*128 + (((quad<<5) + 0 ) ^ xsw));
      int4 gb = *(const int4*)(cg + col*128 + (((quad<<5) + 16) ^ xsw));
      int4 ua = *(const int4*)(cu + col*128 + (((quad<<5) + 0 ) ^ xsw));
      int4 ub = *(const int4*)(cu + col*128 + (((quad<<5) + 16) ^ xsw));
      afg[s][0] = (short)lutg[ga.x]; afg[s][1] = (short)lutg[ga.y];
      afg[s][2] = (short)lutg[ga.z]; afg[s][3] = (short)lutg[ga.w];
      afg[s][4] = (short)lutg[gb.x]; afg[s][5] = (short)lutg[gb.y];
      afg[s][6] = (short)lutg[gb.z]; afg[s][7] = (short)lutg[gb.w];
      afu[s][0] = (short)lutu[ua.x]; afu[s][1] = (short)lutu[ua.y];
      afu[s][2] = (short)lutu[ua.z]; afu[s][3] = (short)lutu[ua.w];
      afu[s][4] = (short)lutu[ub.x]; afu[s][5] = (short)lutu[ub.y];
      afu[s][6] = (short)lutu[ub.z]; afu[s][7] = (short)lutu[ub.w];
    }

    // x fragments from k-blocked layout (shared across strips)
    const size_t xoff = ((size_t)((k0 >> 3) + quad) * 64 + col) * 8;
    short8 bgv[4], buv[4];
    #pragma unroll
    for (int t = 0; t < 4; ++t) {
      bgv[t] = __builtin_bit_cast(short8, *(const int4*)(xgB + xoff + t*128));
      buv[t] = __builtin_bit_cast(short8, *(const int4*)(xuB + xoff + t*128));
    }
    __builtin_amdgcn_sched_barrier(0);   // keep stage AFTER x loads (vmcnt order)

    // stage next chunk into buf p^1
    const int kn = (it == NIT-1) ? kbeg : k0 + 32;
    #pragma unroll
    for (int s = 0; s < 2; ++s)
      #pragma unroll
      for (int h = 0; h < 2; ++h) {
        gll16(gsrc[s][h] + kn, (char*)&cbuf[w][p^1][0][s][0] + h*1024);
        gll16(usrc[s][h] + kn, (char*)&cbuf[w][p^1][1][s][0] + h*1024);
      }

    #pragma unroll
    for (int t = 0; t < 4; ++t)
      #pragma unroll
      for (int s = 0; s < 2; ++s) {
        accg[s][t] = __builtin_amdgcn_mfma_f32_16x16x32_bf16(afg[s], bgv[t], accg[s][t], 0, 0, 0);
        accu[s][t] = __builtin_amdgcn_mfma_f32_16x16x32_bf16(afu[s], buv[t], accu[s][t], 0, 0, 0);
      }
    p ^= 1;
  }

  // cross-wave K-half reduce
  if (w == 1) {
    #pragma unroll
    for (int s = 0; s < 2; ++s)
      #pragma unroll
      for (int t = 0; t < 4; ++t) {
        red[(s*4+t)*2+0][lane] = accg[s][t];
        red[(s*4+t)*2+1][lane] = accu[s][t];
      }
  }
  __syncthreads();
  if (w == 0) {
    #pragma unroll
    for (int s = 0; s < 2; ++s) {
      const int mrow = m0 + s*16 + quad*4;
      float sg[4], su[4], sd[4];
      #pragma unroll
      for (int r = 0; r < 4; ++r) {
        sg[r] = 0.02f * gsl[mrow + r];
        su[r] = 0.02f * usl[mrow + r];
        sd[r] = dsr[mrow + r];
      }
      #pragma unroll
      for (int t = 0; t < 4; ++t) {
        f32x4 ag = accg[s][t] + red[(s*4+t)*2+0][lane];
        f32x4 au = accu[s][t] + red[(s*4+t)*2+1][lane];
        int b = t*16 + col;
        float g0 = ag[0]*sg[0], u0 = au[0]*su[0];
        float g1 = ag[1]*sg[1], u1 = au[1]*su[1];
        float g2 = ag[2]*sg[2], u2 = au[2]*su[2];
        float g3 = ag[3]*sg[3], u3 = au[3]*su[3];
        ushort4 hv;
        hv.x = f2bf((g0 / (1.f + __expf(-g0))) * u0 * sd[0]);
        hv.y = f2bf((g1 / (1.f + __expf(-g1))) * u1 * sd[1]);
        hv.z = f2bf((g2 / (1.f + __expf(-g2))) * u2 * sd[2]);
        hv.w = f2bf((g3 / (1.f + __expf(-g3))) * u3 * sd[3]);
        // k-blocked hidden: unit (i>>3)*64+b, sub-offset i&7
        *(ushort4*)(hidB + ((size_t)((mrow >> 3)*64 + b))*8 + (quad & 1)*4) = hv;
      }
    }
  }
}

// ---------------------------------------------------------------------------
// down: out[b][h] = 0.02*dsl[h] * sum_i hidden[b][i]*lut_d[dw[h,i]]
// Same structure: 2-wave blocks, 32 h-rows, per-wave K = ID/DKS/2 = 896,
// staged+swizzled codes, k-blocked hidden reads, LDS reduce, atomics.
// grid (HD/32, DKS) = (128, 8). LDS: 8K LUT + 16K codes + 8K red = 32KB.
// ---------------------------------------------------------------------------
__global__ __launch_bounds__(128, 2) void down_kernel(
    const int* __restrict__ dw, const float* __restrict__ lutd_f,
    const unsigned short* __restrict__ hidB,
    const float* __restrict__ dsl,
    float* __restrict__ out)
{
  __shared__ unsigned short lutd[NLUTN];
  __shared__ __align__(16) int cbuf[2][2][2][512];   // [wave][buf][strip]
  __shared__ f32x4 red[8][64];

  const int tid  = threadIdx.x;
  const int lane = tid & 63;
  const int w    = tid >> 6;

  for (int i = tid; i < NLUTN/4; i += 128) {
    float4 d = ((const float4*)lutd_f)[i];
    ((ushort4*)lutd)[i] = make_ushort4(f2bf(d.x), f2bf(d.y), f2bf(d.z), f2bf(d.w));
  }
  __syncthreads();

  const int col  = lane & 15;
  const int quad = lane >> 4;
  const int m0   = blockIdx.x * 32;
  const int r8   = lane >> 3;
  const int j    = lane & 7;
  const int jx   = (j ^ r8) << 2;
  const int xsw  = (col & 7) << 4;

  const int kbeg = blockIdx.y * (ID/DKS) + w * (ID/DKS/2);  // 896 per wave
  const int NIT  = (ID/DKS/2) / 32;                         // 28

  const int* dsrc[2][2];
  #pragma unroll
  for (int s = 0; s < 2; ++s)
    #pragma unroll
    for (int h = 0; h < 2; ++h) {
      int row = m0 + s*16 + h*8 + r8;
      dsrc[s][h] = dw + (size_t)row * ID + jx;
    }

  const f32x4 z = {0.f, 0.f, 0.f, 0.f};
  f32x4 acc[2][4] = {{z,z,z,z},{z,z,z,z}};

  #pragma unroll
  for (int s = 0; s < 2; ++s)
    #pragma unroll
    for (int h = 0; h < 2; ++h)
      gll16(dsrc[s][h] + kbeg, (char*)&cbuf[w][0][s][0] + h*1024);

  int p = 0;
  for (int it = 0; it < NIT; ++it) {
    const int k0 = kbeg + it*32;
    asm volatile("s_waitcnt vmcnt(0)" ::: "memory");
    __builtin_amdgcn_sched_barrier(0);

    short8 af[2];
    #pragma unroll
    for (int s = 0; s < 2; ++s) {
      const char* cd = (const char*)&cbuf[w][p][s][0];
      int4 da = *(const int4*)(cd + col*128 + (((quad<<5) + 0 ) ^ xsw));
      int4 db = *(const int4*)(cd + col*128 + (((quad<<5) + 16) ^ xsw));
      af[s][0] = (short)lutd[da.x]; af[s][1] = (short)lutd[da.y];
      af[s][2] = (short)lutd[da.z]; af[s][3] = (short)lutd[da.w];
      af[s][4] = (short)lutd[db.x]; af[s][5] = (short)lutd[db.y];
      af[s][6] = (short)lutd[db.z]; af[s][7] = (short)lutd[db.w];
    }

    const size_t xoff = ((size_t)((k0 >> 3) + quad) * 64 + col) * 8;
    short8 bh[4];
    #pragma unroll
    for (int t = 0; t < 4; ++t)
      bh[t] = __builtin_bit_cast(short8, *(const int4*)(hidB + xoff + t*128));
    __builtin_amdgcn_sched_barrier(0);

    const int kn = (it == NIT-1) ? kbeg : k0 + 32;
    #pragma unroll
    for (int s = 0; s < 2; ++s)
      #pragma unroll
      for (int h = 0; h < 2; ++h)
        gll16(dsrc[s][h] + kn, (char*)&cbuf[w][p^1][s][0] + h*1024);

    #pragma unroll
    for (int t = 0; t < 4; ++t)
      #pragma unroll
      for (int s = 0; s < 2; ++s)
        acc[s][t] = __builtin_amdgcn_mfma_f32_16x16x32_bf16(af[s], bh[t], acc[s][t], 0, 0, 0);
    p ^= 1;
  }

  if (w == 1) {
    #pragma unroll
    for (int s = 0; s < 2; ++s)
      #pragma unroll
      for (int t = 0; t < 4; ++t)
        red[s*4+t][lane] = acc[s][t];
  }
  __syncthreads();
  if (w == 0) {
    #pragma unroll
    for (int s = 0; s < 2; ++s) {
      const int mrow = m0 + s*16 + quad*4;
      float sc[4];
      #pragma unroll
      for (int r = 0; r < 4; ++r) sc[r] = 0.02f * dsl[mrow + r];
      #pragma unroll
      for (int t = 0; t < 4; ++t) {
        f32x4 a = acc[s][t] + red[s*4+t][lane];
        int b = t*16 + col;
        #pragma unroll
        for (int r = 0; r < 4; ++r)
          atomicAdd(&out[(size_t)b * HD + mrow + r], a[r] * sc[r]);
      }
    }
  }
}

// ---------------------------------------------------------------------------
extern "C" void kernel_launch(void* const* d_in, const int* in_sizes, int n_in,
                              void* d_out, int out_size, void* d_ws, size_t ws_size,
                              hipStream_t stream) {
  const float* x    = (const float*)d_in[0];
  const float* lutg = (const float*)d_in[1];
  const float* lutu = (const float*)d_in[2];
  const float* lutd = (const float*)d_in[3];
  const int*   gw   = (const int*)d_in[4];
  const int*   uw   = (const int*)d_in[5];
  const int*   dw   = (const int*)d_in[6];
  const float* gsl  = (const float*)d_in[7];
  const float* gsr  = (const float*)d_in[8];
  const float* usl  = (const float*)d_in[9];
  const float* usr  = (const float*)d_in[10];
  const float* dsl  = (const float*)d_in[11];
  const float* dsr  = (const float*)d_in[12];
  float* out = (float*)d_out;

  // ws layout: xgB (512KB) | xuB (512KB) | hidB (1.75MB)
  unsigned short* xgB  = (unsigned short*)d_ws;
  unsigned short* xuB  = xgB + (size_t)NB * HD;
  unsigned short* hidB = xuB + (size_t)NB * HD;

  hipMemsetAsync(d_out, 0, (size_t)NB * HD * sizeof(float), stream);
  prep_kernel<<<(NB*HD/8 + 255)/256, 256, 0, stream>>>(x, gsr, usr, xgB, xuB);
  gate_up_kernel<<<ID/32, 128, 0, stream>>>(gw, uw, lutg, lutu, xgB, xuB,
                                            gsl, usl, dsr, hidB);
  down_kernel<<<dim3(HD/32, DKS), 128, 0, stream>>>(dw, lutd, hidB, dsl, out);
}